// Round 11
// baseline (244.784 us; speedup 1.0000x reference)
//
#include <hip/hip_runtime.h>
#include <hip/hip_bf16.h>
#include <math.h>

#define B_SZ 2048
#define L_SEQ 8
#define DMODEL 128
#define DSTATE 64
#define HEADDIM 32
#define DCONV 4
#define DINNER 256
#define NHEADS 8
#define DCONVCH 384   // DINNER + 2*DSTATE
#define DINPROJ 648   // 2*DINNER + 2*DSTATE + NHEADS
#define NPAD 656      // 41 * 16

typedef short bf16x8 __attribute__((ext_vector_type(8)));
typedef float floatx4 __attribute__((ext_vector_type(4)));

__device__ __forceinline__ float siluf(float x) {
    return x / (1.f + expf(-x));
}
__device__ __forceinline__ float bf2f(unsigned short h) {
    unsigned int u = ((unsigned int)h) << 16;
    return __builtin_bit_cast(float, u);
}
__device__ __forceinline__ unsigned short f2bf(float f) {
    __hip_bfloat16 b = __float2bfloat16(f);
    return __builtin_bit_cast(unsigned short, b);
}
__device__ __forceinline__ void unpack8(bf16x8 v, float* o) {
    #pragma unroll
    for (int j = 0; j < 8; ++j) o[j] = bf2f((unsigned short)v[j]);
}
// async global->LDS, 16B per lane; LDS dest = wave-uniform base + lane*16
__device__ __forceinline__ void gl_lds16(const unsigned short* g, unsigned short* l) {
    __builtin_amdgcn_global_load_lds(
        (const __attribute__((address_space(1))) unsigned int*)g,
        (__attribute__((address_space(3))) unsigned int*)l, 16, 0, 0);
}

// ---------------------------------------------------------------------------
// Prep (small): Win/Wout/attn transposes+casts. 1424 blocks. (frozen)
// ---------------------------------------------------------------------------
__global__ __launch_bounds__(256) void prep_weights(
    const float* __restrict__ st_Win, const float* __restrict__ ex_Win,
    const float* __restrict__ st_Wout, const float* __restrict__ ex_Wout,
    const float* __restrict__ st_normw, const float* __restrict__ ex_normw,
    const float* __restrict__ cs_Wq, const float* __restrict__ cs_Wk,
    const float* __restrict__ cs_Wv, const float* __restrict__ cs_Wo,
    const float* __restrict__ cx_Wq, const float* __restrict__ cx_Wk,
    const float* __restrict__ cx_Wv, const float* __restrict__ cx_Wo,
    unsigned short* __restrict__ winT_st, unsigned short* __restrict__ winT_ex,
    unsigned short* __restrict__ woutT_st, unsigned short* __restrict__ woutT_ex,
    unsigned short* __restrict__ attnWT)
{
    int blk = blockIdx.x;
    if (blk < 656) {
        const float* src = blk < 328 ? st_Win : ex_Win;
        unsigned short* dst = blk < 328 ? winT_st : winT_ex;
        int idx = (blk % 328) * 256 + threadIdx.x;
        if (idx >= NPAD * 128) return;
        int n = idx / 128, k = idx % 128;
        float v = (n < DINPROJ) ? src[k * DINPROJ + n] : 0.f;
        dst[idx] = f2bf(v);
    } else if (blk < 912) {
        const float* src = blk < 784 ? st_Wout : ex_Wout;
        const float* nw  = blk < 784 ? st_normw : ex_normw;
        unsigned short* dst = blk < 784 ? woutT_st : woutT_ex;
        int idx = ((blk - 656) % 128) * 256 + threadIdx.x;
        int n = idx / 256, k = idx % 256;   // dst [128][256]
        dst[idx] = f2bf(src[k * 128 + n] * nw[k]);   // normw folded into Wout
    } else {
        int b2 = blk - 912;
        int mat = b2 >> 6;
        const float* src = mat == 0 ? cs_Wq : mat == 1 ? cs_Wk : mat == 2 ? cs_Wv :
                           mat == 3 ? cs_Wo : mat == 4 ? cx_Wq : mat == 5 ? cx_Wk :
                           mat == 6 ? cx_Wv : cx_Wo;
        int e = (b2 & 63) * 256 + threadIdx.x;
        int n = e >> 7, k = e & 127;
        attnWT[mat * 16384 + n * 128 + k] = f2bf(src[k * 128 + n]);
    }
}

// ---------------------------------------------------------------------------
// Dual Mamba2 v4 (frozen from R8/R10): GEMM1 deduplicated. Register prefetch
// (R9) was a NULL — do not retry. + backfilled mlp_W transpose.
// ---------------------------------------------------------------------------
#define LDK 136
#define LDZ 648
__global__ __launch_bounds__(256, 3) void mamba_dual(
    const float* __restrict__ u_ex, const float* __restrict__ u_st,
    const unsigned short* __restrict__ WinT_ex, const unsigned short* __restrict__ WinT_st,
    const float* __restrict__ convw_ex, const float* __restrict__ convw_st,
    const float* __restrict__ convb_ex, const float* __restrict__ convb_st,
    const float* __restrict__ dtb_ex, const float* __restrict__ dtb_st,
    const float* __restrict__ Alog_ex, const float* __restrict__ Alog_st,
    const float* __restrict__ Dp_ex, const float* __restrict__ Dp_st,
    const unsigned short* __restrict__ WoutT_ex, const unsigned short* __restrict__ WoutT_st,
    unsigned short* __restrict__ out_ex, unsigned short* __restrict__ out_st,
    const float* __restrict__ mlp_W, unsigned short* __restrict__ mlpWt)
{
    const int tid = threadIdx.x;

    __shared__ __align__(16) unsigned short uA[32 * LDK];  // A-frags; coefp+rstd; transpose tile
    __shared__ __align__(16) unsigned short zx[32 * LDZ];
    __shared__ float dtv[4][8][8];
    __shared__ float cum[4][8][8];
    __shared__ float Gm[4][8][8];

    if (blockIdx.x >= 1024) {
        // ---- mlp_W transpose backfill: 2048 blocks of 32x32 ----
        int b2 = blockIdx.x - 1024;
        int n0 = (b2 & 31) * 32, k0 = (b2 >> 5) * 32;
        float* tile = (float*)uA;            // 32*33 floats = 4224 B
        const int c = tid & 31, r0 = tid >> 5;
        for (int rr = r0; rr < 32; rr += 8)
            tile[rr * 33 + c] = mlp_W[(size_t)(k0 + rr) * 1024 + n0 + c];
        __syncthreads();
        for (int rr = r0; rr < 32; rr += 8)
            mlpWt[(size_t)(n0 + rr) * 2048 + k0 + c] = f2bf(tile[c * 33 + rr]);
        return;
    }

    const int which = blockIdx.x >> 9;          // 1024 blocks: 512 per input
    const float* u = which ? u_st : u_ex;
    const unsigned short* WinT = which ? WinT_st : WinT_ex;
    const float* convw = which ? convw_st : convw_ex;
    const float* convb = which ? convb_st : convb_ex;
    const float* dtb = which ? dtb_st : dtb_ex;
    const float* Alog = which ? Alog_st : Alog_ex;
    const float* Dp = which ? Dp_st : Dp_ex;
    const unsigned short* WoutT = which ? WoutT_st : WoutT_ex;
    unsigned short* outf = which ? out_st : out_ex;

    const int lane = tid & 63;
    const int wave = tid >> 6;
    const int l15 = lane & 15;
    const int q8 = (lane >> 4) * 8;
    const int row0 = (lane >> 4) * 4;
    const int grow0 = (blockIdx.x & 511) * 32;  // 32 rows per block

    float* coefp = (float*)uA;          // 2048 floats (8192 B of 8704)
    float* rstdp = coefp + 2048;        // 32 floats

    // stage u (32 rows x 128) as bf16 A-tiles
    #pragma unroll
    for (int it = 0; it < 4; ++it) {
        int i = tid + it * 256;
        int r = i >> 5, k4 = (i & 31) * 4;
        float4 v = *(const float4*)(u + (size_t)(grow0 + r) * DMODEL + k4);
        ushort4 h;
        h.x = f2bf(v.x); h.y = f2bf(v.y); h.z = f2bf(v.z); h.w = f2bf(v.w);
        *(ushort4*)(uA + r * LDK + k4) = h;
    }
    __syncthreads();

    // GEMM1: zxbcdt = u @ Win. Loop over nt only; one B load, two m-tile MFMAs.
    {
        bf16x8 af[2][4];
        #pragma unroll
        for (int mt = 0; mt < 2; ++mt)
            #pragma unroll
            for (int kk = 0; kk < 4; ++kk)
                af[mt][kk] = *(const bf16x8*)(uA + (mt * 16 + l15) * LDK + kk * 32 + q8);
        for (int nt = wave; nt < 41; nt += 4) {
            const unsigned short* bp = WinT + (size_t)(nt * 16 + l15) * 128 + q8;
            bf16x8 bfr[4];
            #pragma unroll
            for (int kk = 0; kk < 4; ++kk) bfr[kk] = *(const bf16x8*)(bp + kk * 32);
            floatx4 acc0 = {0.f, 0.f, 0.f, 0.f};
            floatx4 acc1 = {0.f, 0.f, 0.f, 0.f};
            #pragma unroll
            for (int kk = 0; kk < 4; ++kk) {
                acc0 = __builtin_amdgcn_mfma_f32_16x16x32_bf16(af[0][kk], bfr[kk], acc0, 0, 0, 0);
                acc1 = __builtin_amdgcn_mfma_f32_16x16x32_bf16(af[1][kk], bfr[kk], acc1, 0, 0, 0);
            }
            if (nt == 40) {
                if (l15 < 8) {
                    float dbv = dtb[l15];
                    #pragma unroll
                    for (int r = 0; r < 4; ++r) {
                        int rr0 = row0 + r;
                        float v0 = acc0[r] + dbv;
                        dtv[rr0 >> 3][rr0 & 7][l15] = (v0 > 20.f) ? v0 : log1pf(expf(v0));
                        int rr1 = 16 + row0 + r;
                        float v1 = acc1[r] + dbv;
                        dtv[rr1 >> 3][rr1 & 7][l15] = (v1 > 20.f) ? v1 : log1pf(expf(v1));
                    }
                }
            } else {
                #pragma unroll
                for (int r = 0; r < 4; ++r) {
                    zx[(row0 + r) * LDZ + nt * 16 + l15]      = f2bf(acc0[r]);
                    zx[(16 + row0 + r) * LDZ + nt * 16 + l15] = f2bf(acc1[r]);
                }
            }
        }
    }
    __syncthreads();

    // depthwise conv + SiLU over 32 rows x 384 channels (= 1536 ch-groups)
    float cv[6][8];
    {
        #pragma unroll
        for (int it = 0; it < 6; ++it) {
            int i = tid + it * 256;
            int r = i / 48, g = i % 48;
            int c0 = g * 8;
            int l = r & 7, bloc = r >> 3;
            float s[8];
            float4 cb0 = *(const float4*)(convb + c0);
            float4 cb1 = *(const float4*)(convb + c0 + 4);
            s[0] = cb0.x; s[1] = cb0.y; s[2] = cb0.z; s[3] = cb0.w;
            s[4] = cb1.x; s[5] = cb1.y; s[6] = cb1.z; s[7] = cb1.w;
            #pragma unroll
            for (int k = 0; k < DCONV; ++k) {
                int lp = l + k - (DCONV - 1);
                if (lp >= 0) {
                    bf16x8 v = *(const bf16x8*)(zx + (bloc * 8 + lp) * LDZ + 256 + c0);
                    float vf[8];
                    unpack8(v, vf);
                    float4 w0 = *(const float4*)(convw + k * DCONVCH + c0);
                    float4 w1 = *(const float4*)(convw + k * DCONVCH + c0 + 4);
                    s[0] += vf[0] * w0.x; s[1] += vf[1] * w0.y;
                    s[2] += vf[2] * w0.z; s[3] += vf[3] * w0.w;
                    s[4] += vf[4] * w1.x; s[5] += vf[5] * w1.y;
                    s[6] += vf[6] * w1.z; s[7] += vf[7] * w1.w;
                }
            }
            #pragma unroll
            for (int j = 0; j < 8; ++j) cv[it][j] = siluf(s[j]);
        }
    }
    __syncthreads();
    {
        #pragma unroll
        for (int it = 0; it < 6; ++it) {
            int i = tid + it * 256;
            int r = i / 48, c0 = (i % 48) * 8;
            bf16x8 o;
            #pragma unroll
            for (int j = 0; j < 8; ++j) o[j] = (short)f2bf(cv[it][j]);
            *(bf16x8*)(zx + r * LDZ + 256 + c0) = o;
        }
        if (tid < 32) {  // dt cumsum (dtv ready since GEMM1 barrier)
            int bloc = tid >> 3, h = tid & 7;
            float c = 0.f;
            for (int l = 0; l < L_SEQ; ++l) { c += dtv[bloc][l][h]; cum[bloc][l][h] = c; }
        }
    }
    __syncthreads();

    // Gram matrix G[t][s] = B_s . C_t  (4 blocs x 8 x 8 = 256 threads)
    {
        int bloc = tid >> 6, t = (tid >> 3) & 7, s = tid & 7;
        float a = 0.f;
        #pragma unroll
        for (int n = 0; n < DSTATE; n += 8) {
            bf16x8 bv = *(const bf16x8*)(zx + (bloc * 8 + s) * LDZ + 512 + n);
            bf16x8 cvv = *(const bf16x8*)(zx + (bloc * 8 + t) * LDZ + 576 + n);
            float bf_[8], cf_[8];
            unpack8(bv, bf_); unpack8(cvv, cf_);
            #pragma unroll
            for (int j = 0; j < 8; ++j) a += bf_[j] * cf_[j];
        }
        Gm[bloc][t][s] = a;
    }
    __syncthreads();

    // coef[t][s][h] = G[t][s] * exp(A*(cum_t - cum_s)) * dt_s   (2048 entries)
    #pragma unroll
    for (int it = 0; it < 8; ++it) {
        int i = tid + it * 256;
        int bloc = i >> 9, t = (i >> 6) & 7, s = (i >> 3) & 7, h = i & 7;
        float A = -expf(Alog[h]);
        coefp[i] = (s <= t)
            ? Gm[bloc][t][s] * expf(A * (cum[bloc][t][h] - cum[bloc][s][h])) * dtv[bloc][s][h]
            : 0.f;
    }
    __syncthreads();

    // SSM y-accum + gate + sum-of-squares, all in registers (4 sub-iters)
    float pj[4];
    bf16x8 yo[4];
    int rF[4], c0F[4];
    {
        #pragma unroll
        for (int it = 0; it < 4; ++it) {
            int i = tid + it * 256;
            int r = i >> 5, g = i & 31;
            int c0 = g * 8, h = g >> 2;
            int bloc = r >> 3, t = r & 7;
            float acc[8];
            {
                bf16x8 xv = *(const bf16x8*)(zx + r * LDZ + 256 + c0);
                float xf[8]; unpack8(xv, xf);
                float d = Dp[h];
                #pragma unroll
                for (int j = 0; j < 8; ++j) acc[j] = d * xf[j];
            }
            for (int s = 0; s <= t; ++s) {
                float cf = coefp[((bloc * 8 + t) * 8 + s) * 8 + h];
                bf16x8 xv = *(const bf16x8*)(zx + (bloc * 8 + s) * LDZ + 256 + c0);
                float xf[8]; unpack8(xv, xf);
                #pragma unroll
                for (int j = 0; j < 8; ++j) acc[j] += cf * xf[j];
            }
            bf16x8 zv = *(const bf16x8*)(zx + r * LDZ + c0);
            float zf[8]; unpack8(zv, zf);
            float p = 0.f;
            #pragma unroll
            for (int j = 0; j < 8; ++j) {
                float y = acc[j] * siluf(zf[j]);
                p += y * y;
                yo[it][j] = (short)f2bf(y);
            }
            pj[it] = p; rF[it] = r; c0F[it] = c0;
        }
    }
    // row sum-of-squares: each 32-lane half shares one row -> butterfly reduce
    #pragma unroll
    for (int m = 1; m < 32; m <<= 1) {
        #pragma unroll
        for (int it = 0; it < 4; ++it) pj[it] += __shfl_xor(pj[it], m);
    }
    if ((tid & 31) == 0) {
        #pragma unroll
        for (int it = 0; it < 4; ++it)
            rstdp[rF[it]] = rsqrtf(pj[it] * (1.f / 256.f) + 1e-5f);
    }
    __syncthreads();   // all x-reads done + rstd visible
    #pragma unroll
    for (int it = 0; it < 4; ++it)
        *(bf16x8*)(zx + rF[it] * LDZ + 256 + c0F[it]) = yo[it];
    __syncthreads();

    // GEMM2: out = rstd[row] * (y @ WoutT') (2 m-tiles x 8 n-tiles)
    {
        bf16x8 af[2][8];
        #pragma unroll
        for (int mt = 0; mt < 2; ++mt)
            #pragma unroll
            for (int kk = 0; kk < 8; ++kk)
                af[mt][kk] = *(const bf16x8*)(zx + (mt * 16 + l15) * LDZ + 256 + kk * 32 + q8);
        #pragma unroll
        for (int ni = 0; ni < 2; ++ni) {
            int nt = wave * 2 + ni;
            const unsigned short* bp = WoutT + (size_t)(nt * 16 + l15) * 256 + q8;
            bf16x8 bfr[8];
            #pragma unroll
            for (int kk = 0; kk < 8; ++kk) bfr[kk] = *(const bf16x8*)(bp + kk * 32);
            #pragma unroll
            for (int mt = 0; mt < 2; ++mt) {
                floatx4 acc = {0.f, 0.f, 0.f, 0.f};
                #pragma unroll
                for (int kk = 0; kk < 8; ++kk)
                    acc = __builtin_amdgcn_mfma_f32_16x16x32_bf16(af[mt][kk], bfr[kk], acc, 0, 0, 0);
                #pragma unroll
                for (int r = 0; r < 4; ++r) {
                    int rr = mt * 16 + row0 + r;
                    outf[(size_t)(grow0 + rr) * DMODEL + nt * 16 + l15] =
                        f2bf(acc[r] * rstdp[rr]);
                }
            }
        }
    }
}

// ---------------------------------------------------------------------------
// Cross-attentions, 4 batches per block (M=32), grid B/4 = 512.
// v3 (frozen from R10): attv aliased onto Qs (3 blocks/CU) + wave-parallel
// softmax; P zero-band pre-initialized once.
// ---------------------------------------------------------------------------
#define ASTR 136
#define VSTR 40
#define PSTR 40
__global__ __launch_bounds__(256, 3) void attn_kernel(
    const unsigned short* __restrict__ st_f,
    const unsigned short* __restrict__ exp_f,
    const unsigned short* __restrict__ WT,
    const float* __restrict__ cs_bq, const float* __restrict__ cs_bk,
    const float* __restrict__ cs_bv, const float* __restrict__ cs_bo,
    const float* __restrict__ cx_bq, const float* __restrict__ cx_bk,
    const float* __restrict__ cx_bv, const float* __restrict__ cx_bo,
    __hip_bfloat16* __restrict__ x)
{
    const int tid = threadIdx.x;
    const int lane = tid & 63, wave = tid >> 6;
    const int l15 = lane & 15;
    const int q8 = (lane >> 4) * 8;
    const int row0 = (lane >> 4) * 4;
    const int grow0 = blockIdx.x * 32;
    const int b0 = blockIdx.x * 4;
    const float scale = 0.08838834764831845f;

    __shared__ __align__(16) unsigned short stf[32 * ASTR];
    __shared__ __align__(16) unsigned short exf[32 * ASTR];
    __shared__ __align__(16) unsigned short Qs[32 * ASTR];   // aliased by attv
    __shared__ __align__(16) unsigned short Ks[32 * ASTR];
    __shared__ __align__(16) unsigned short Vt[128 * VSTR];  // [chan][kvrow 0..31]
    __shared__ __align__(16) unsigned short P[32 * PSTR];
    __shared__ float Ss[32][33];
    unsigned short* attv = Qs;   // Qs last read in scores; attv written post-barrier

    #pragma unroll
    for (int it = 0; it < 2; ++it) {
        int i = tid + it * 256;
        int r = i >> 4, c8 = (i & 15) * 8;
        *(uint4*)(stf + r * ASTR + c8) = *(const uint4*)(st_f + (size_t)(grow0 + r) * 128 + c8);
        *(uint4*)(exf + r * ASTR + c8) = *(const uint4*)(exp_f + (size_t)(grow0 + r) * 128 + c8);
    }
    // P zero-band init (once): the per-row nonzero band is pass-invariant.
    #pragma unroll
    for (int i = tid; i < 32 * 32; i += 256)
        P[(i >> 5) * PSTR + (i & 31)] = 0;
    __syncthreads();

    #pragma unroll
    for (int pass = 0; pass < 2; ++pass) {
        const unsigned short* qsrc = pass ? exf : stf;
        const unsigned short* kvsrc = pass ? stf : exf;
        const unsigned short* Wq = WT + (size_t)pass * 4 * 16384;
        const unsigned short* Wk = Wq + 16384;
        const unsigned short* Wv = Wq + 32768;
        const unsigned short* Wo = Wq + 49152;
        const float* bq = pass ? cx_bq : cs_bq;
        const float* bk = pass ? cx_bk : cs_bk;
        const float* bv = pass ? cx_bv : cs_bv;
        const float* bo = pass ? cx_bo : cs_bo;

        // --- Q/K/V projections (2 m-tiles x 2 n-tiles per wave) ---
        {
            bf16x8 aq[2][4], akv[2][4];
            #pragma unroll
            for (int mt = 0; mt < 2; ++mt)
                #pragma unroll
                for (int kk = 0; kk < 4; ++kk) {
                    aq[mt][kk]  = *(const bf16x8*)(qsrc  + (mt * 16 + l15) * ASTR + kk * 32 + q8);
                    akv[mt][kk] = *(const bf16x8*)(kvsrc + (mt * 16 + l15) * ASTR + kk * 32 + q8);
                }
            #pragma unroll
            for (int ni = 0; ni < 2; ++ni) {
                int nc = (wave * 2 + ni) * 16 + l15;
                floatx4 aq0 = {0,0,0,0}, aq1 = {0,0,0,0};
                floatx4 ak0 = {0,0,0,0}, ak1 = {0,0,0,0};
                floatx4 av0 = {0,0,0,0}, av1 = {0,0,0,0};
                #pragma unroll
                for (int kk = 0; kk < 4; ++kk) {
                    bf16x8 wqf = *(const bf16x8*)(Wq + (size_t)nc * 128 + kk * 32 + q8);
                    bf16x8 wkf = *(const bf16x8*)(Wk + (size_t)nc * 128 + kk * 32 + q8);
                    bf16x8 wvf = *(const bf16x8*)(Wv + (size_t)nc * 128 + kk * 32 + q8);
                    aq0 = __builtin_amdgcn_mfma_f32_16x16x32_bf16(aq[0][kk],  wqf, aq0, 0, 0, 0);
                    aq1 = __builtin_amdgcn_mfma_f32_16x16x32_bf16(aq[1][kk],  wqf, aq1, 0, 0, 0);
                    ak0 = __builtin_amdgcn_mfma_f32_16x16x32_bf16(akv[0][kk], wkf, ak0, 0, 0, 0);
                    ak1 = __builtin_amdgcn_mfma_f32_16x16x32_bf16(akv[1][kk], wkf, ak1, 0, 0, 0);
                    av0 = __builtin_amdgcn_mfma_f32_16x16x32_bf16(akv[0][kk], wvf, av0, 0, 0, 0);
                    av1 = __builtin_amdgcn_mfma_f32_16x16x32_bf16(akv[1][kk], wvf, av1, 0, 0, 0);
                }
                float bqv = bq[nc], bkv = bk[nc], bvv = bv[nc];
                #pragma unroll
                for (int r = 0; r < 4; ++r) {
                    Qs[(row0 + r) * ASTR + nc]      = f2bf(aq0[r] + bqv);
                    Qs[(16 + row0 + r) * ASTR + nc] = f2bf(aq1[r] + bqv);
                    Ks[(row0 + r) * ASTR + nc]      = f2bf(ak0[r] + bkv);
                    Ks[(16 + row0 + r) * ASTR + nc] = f2bf(ak1[r] + bkv);
                    Vt[nc * VSTR + row0 + r]        = f2bf(av0[r] + bvv);
                    Vt[nc * VSTR + 16 + row0 + r]   = f2bf(av1[r] + bvv);
                }
            }
        }
        __syncthreads();

        // --- scores: S(32x32) = Q @ K^T; wave w does tile (w>>1, w&1) ---
        {
            int mtS = wave >> 1, ntS = wave & 1;
            floatx4 s = {0,0,0,0};
            #pragma unroll
            for (int kk = 0; kk < 4; ++kk) {
                bf16x8 a = *(const bf16x8*)(Qs + (mtS * 16 + l15) * ASTR + kk * 32 + q8);
                bf16x8 b = *(const bf16x8*)(Ks + (ntS * 16 + l15) * ASTR + kk * 32 + q8);
                s = __builtin_amdgcn_mfma_f32_16x16x32_bf16(a, b, s, 0, 0, 0);
            }
            #pragma unroll
            for (int r = 0; r < 4; ++r)
                Ss[mtS * 16 + row0 + r][ntS * 16 + l15] = s[r];
        }
        __syncthreads();

        // --- softmax, wave-parallel: thread = (row r, col c); 8-lane groups ---
        {
            int r = tid >> 3, c = tid & 7, c0 = (r >> 3) * 8;
            float v = Ss[r][c0 + c] * scale;
            float mx = v;
            mx = fmaxf(mx, __shfl_xor(mx, 1));
            mx = fmaxf(mx, __shfl_xor(mx, 2));
            mx = fmaxf(mx, __shfl_xor(mx, 4));
            float e = expf(v - mx);
            float sum = e;
            sum += __shfl_xor(sum, 1);
            sum += __shfl_xor(sum, 2);
            sum += __shfl_xor(sum, 4);
            P[r * PSTR + c0 + c] = f2bf(e / sum);
        }
        __syncthreads();

        // --- O = P(32x32) @ V(32x128): per wave 2 n-tiles x 2 m-tiles ---
        {
            #pragma unroll
            for (int ni = 0; ni < 2; ++ni) {
                int nc = (wave * 2 + ni) * 16 + l15;
                bf16x8 bv_ = *(const bf16x8*)(Vt + nc * VSTR + q8);
                #pragma unroll
                for (int mt = 0; mt < 2; ++mt) {
                    bf16x8 ap = *(const bf16x8*)(P + (mt * 16 + l15) * PSTR + q8);
                    floatx4 o = {0,0,0,0};
                    o = __builtin_amdgcn_mfma_f32_16x16x32_bf16(ap, bv_, o, 0, 0, 0);
                    #pragma unroll
                    for (int r = 0; r < 4; ++r)
                        attv[(mt * 16 + row0 + r) * ASTR + nc] = f2bf(o[r]);
                }
            }
        }
        __syncthreads();

        // --- Wo projection -> x ---
        {
            bf16x8 ao[2][4];
            #pragma unroll
            for (int mt = 0; mt < 2; ++mt)
                #pragma unroll
                for (int kk = 0; kk < 4; ++kk)
                    ao[mt][kk] = *(const bf16x8*)(attv + (mt * 16 + l15) * ASTR + kk * 32 + q8);
            #pragma unroll
            for (int ni = 0; ni < 2; ++ni) {
                int nc = (wave * 2 + ni) * 16 + l15;
                floatx4 a0 = {0,0,0,0}, a1 = {0,0,0,0};
                #pragma unroll
                for (int kk = 0; kk < 4; ++kk) {
                    bf16x8 wof = *(const bf16x8*)(Wo + (size_t)nc * 128 + kk * 32 + q8);
                    a0 = __builtin_amdgcn_mfma_f32_16x16x32_bf16(ao[0][kk], wof, a0, 0, 0, 0);
                    a1 = __builtin_amdgcn_mfma_f32_16x16x32_bf16(ao[1][kk], wof, a1, 0, 0, 0);
                }
                float bov = bo[nc];
                #pragma unroll
                for (int r = 0; r < 4; ++r) {
                    int rr0 = row0 + r;
                    int rr1 = 16 + row0 + r;
                    x[(size_t)(b0 + (rr0 >> 3)) * 2048 + (rr0 & 7) * 256 + pass * 128 + nc] =
                        __float2bfloat16(a0[r] + bov);
                    x[(size_t)(b0 + (rr1 >> 3)) * 2048 + (rr1 & 7) * 256 + pass * 128 + nc] =
                        __float2bfloat16(a1[r] + bov);
                }
            }
        }
        __syncthreads();
    }
}

// ---------------------------------------------------------------------------
// MLP via MFMA v6: 64x64 tile, BK=64, 4-deep counted-vmcnt pipeline:
// 3 tiles in flight past the computing one (vmcnt(12) ~= 3 iters of cover
// ~= full HBM latency). LDS 64 KB -> 2 blocks/CU (unchanged residency,
// grid 512 = 2/CU). Epilogue drains 12->8->4->0. 512 blocks.
// ---------------------------------------------------------------------------
__global__ __launch_bounds__(256, 2) void mlp_mfma(
    const unsigned short* __restrict__ X,   // [2048][2048] bf16
    const unsigned short* __restrict__ Wt,  // [1024][2048] bf16
    const float* __restrict__ bias,
    float* __restrict__ out)                // [2048][1024]
{
    __shared__ __align__(16) unsigned short As[4][64 * 64];
    __shared__ __align__(16) unsigned short Bs[4][64 * 64];
    const int tid = threadIdx.x;
    const int wave = tid >> 6, lane = tid & 63;
    const int wm = (wave >> 1) * 32, wn = (wave & 1) * 32;
    const int bm = blockIdx.y * 64, bn = blockIdx.x * 64;
    const int l15 = lane & 15, q8 = (lane >> 4) * 8;

    const int c0i = tid, c1i = tid + 256;
    const int r0s = c0i >> 3, c0s = ((c0i & 7) ^ (r0s & 7)) * 8;
    const int r1s = c1i >> 3, c1s = ((c1i & 7) ^ (r1s & 7)) * 8;
    const unsigned short* gA0 = X + (size_t)(bm + r0s) * 2048 + c0s;
    const unsigned short* gA1 = X + (size_t)(bm + r1s) * 2048 + c1s;
    const unsigned short* gB0 = Wt + (size_t)(bn + r0s) * 2048 + c0s;
    const unsigned short* gB1 = Wt + (size_t)(bn + r1s) * 2048 + c1s;

    floatx4 acc[2][2];
    #pragma unroll
    for (int i = 0; i < 2; ++i)
        #pragma unroll
        for (int j = 0; j < 2; ++j) acc[i][j] = (floatx4){0.f, 0.f, 0.f, 0.f};

    const int ra0 = wm + l15, ra1 = wm + 16 + l15;
    const int rb0 = wn + l15, rb1 = wn + 16 + l15;

    // prologue: tiles 0..3 in flight (tile-grouped, 4 loads per tile/thread)
    #pragma unroll
    for (int p = 0; p < 4; ++p) {
        gl_lds16(gA0 + p * 64, As[p] + c0i * 8);
        gl_lds16(gA1 + p * 64, As[p] + c1i * 8);
        gl_lds16(gB0 + p * 64, Bs[p] + c0i * 8);
        gl_lds16(gB1 + p * 64, Bs[p] + c1i * 8);
    }

#define MLP_COMPUTE(Ac, Bc)                                                    \
    {                                                                          \
        _Pragma("unroll")                                                      \
        for (int ks = 0; ks < 2; ++ks) {                                       \
            int xx = ks * 4 + (q8 >> 3);                                       \
            bf16x8 a0 = *(const bf16x8*)((Ac) + (ra0 * 8 + (xx ^ (ra0 & 7))) * 8); \
            bf16x8 a1 = *(const bf16x8*)((Ac) + (ra1 * 8 + (xx ^ (ra1 & 7))) * 8); \
            bf16x8 b0 = *(const bf16x8*)((Bc) + (rb0 * 8 + (xx ^ (rb0 & 7))) * 8); \
            bf16x8 b1 = *(const bf16x8*)((Bc) + (rb1 * 8 + (xx ^ (rb1 & 7))) * 8); \
            acc[0][0] = __builtin_amdgcn_mfma_f32_16x16x32_bf16(a0, b0, acc[0][0], 0, 0, 0); \
            acc[0][1] = __builtin_amdgcn_mfma_f32_16x16x32_bf16(a0, b1, acc[0][1], 0, 0, 0); \
            acc[1][0] = __builtin_amdgcn_mfma_f32_16x16x32_bf16(a1, b0, acc[1][0], 0, 0, 0); \
            acc[1][1] = __builtin_amdgcn_mfma_f32_16x16x32_bf16(a1, b1, acc[1][1], 0, 0, 0); \
        }                                                                      \
    }

    // main loop t = 0..28: wait my tile-t loads (3 younger tiles stay in
    // flight), barrier (all waves' tile-t landed), compute, barrier (buf
    // free), refill with tile t+4.
    for (int t = 0; t < 29; ++t) {
        asm volatile("s_waitcnt vmcnt(12)" ::: "memory");
        __builtin_amdgcn_sched_barrier(0);
        __builtin_amdgcn_s_barrier();
        MLP_COMPUTE(As[t & 3], Bs[t & 3])
        __builtin_amdgcn_sched_barrier(0);
        __builtin_amdgcn_s_barrier();
        if (t < 28) {
            int k0 = (t + 4) * 64;
            gl_lds16(gA0 + k0, As[t & 3] + c0i * 8);
            gl_lds16(gA1 + k0, As[t & 3] + c1i * 8);
            gl_lds16(gB0 + k0, Bs[t & 3] + c0i * 8);
            gl_lds16(gB1 + k0, Bs[t & 3] + c1i * 8);
        }
    }
    // epilogue: t = 29 (tiles 30,31 outstanding), 30, 31
    asm volatile("s_waitcnt vmcnt(8)" ::: "memory");
    __builtin_amdgcn_sched_barrier(0);
    __builtin_amdgcn_s_barrier();
    MLP_COMPUTE(As[1], Bs[1])
    asm volatile("s_waitcnt vmcnt(4)" ::: "memory");
    __builtin_amdgcn_sched_barrier(0);
    __builtin_amdgcn_s_barrier();
    MLP_COMPUTE(As[2], Bs[2])
    asm volatile("s_waitcnt vmcnt(0)" ::: "memory");
    __builtin_amdgcn_sched_barrier(0);
    __builtin_amdgcn_s_barrier();
    MLP_COMPUTE(As[3], Bs[3])
#undef MLP_COMPUTE

    const int row0 = (lane >> 4) * 4;
    #pragma unroll
    for (int j = 0; j < 2; ++j) {
        int col = bn + wn + j * 16 + l15;
        float bv = bias[col];
        #pragma unroll
        for (int r = 0; r < 4; ++r) {
            out[(size_t)(bm + wm + row0 + r) * 1024 + col] = acc[0][j][r] + bv;
            out[(size_t)(bm + wm + 16 + row0 + r) * 1024 + col] = acc[1][j][r] + bv;
        }
    }
}

extern "C" void kernel_launch(void* const* d_in, const int* in_sizes, int n_in,
                              void* d_out, int out_size, void* d_ws, size_t ws_size,
                              hipStream_t stream) {
    const float* st_feature = (const float*)d_in[0];
    const float* exp_feature = (const float*)d_in[1];
    const float* st_Win = (const float*)d_in[2];
    const float* st_convw = (const float*)d_in[3];
    const float* st_convb = (const float*)d_in[4];
    const float* st_dtb = (const float*)d_in[5];
    const float* st_Alog = (const float*)d_in[6];
    const float* st_D = (const float*)d_in[7];
    const float* st_normw = (const float*)d_in[8];
    const float* st_Wout = (const float*)d_in[9];
    const float* ex_Win = (const float*)d_in[10];
    const float* ex_convw = (const float*)d_in[11];
    const float* ex_convb = (const float*)d_in[12];
    const float* ex_dtb = (const float*)d_in[13];
    const float* ex_Alog = (const float*)d_in[14];
    const float* ex_D = (const float*)d_in[15];
    const float* ex_normw = (const float*)d_in[16];
    const float* ex_Wout = (const float*)d_in[17];
    const float* cx_Wq = (const float*)d_in[18]; const float* cx_bq = (const float*)d_in[19];
    const float* cx_Wk = (const float*)d_in[20]; const float* cx_bk = (const float*)d_in[21];
    const float* cx_Wv = (const float*)d_in[22]; const float* cx_bv = (const float*)d_in[23];
    const float* cx_Wo = (const float*)d_in[24]; const float* cx_bo = (const float*)d_in[25];
    const float* cs_Wq = (const float*)d_in[26]; const float* cs_bq = (const float*)d_in[27];
    const float* cs_Wk = (const float*)d_in[28]; const float* cs_bk = (const float*)d_in[29];
    const float* cs_Wv = (const float*)d_in[30]; const float* cs_bv = (const float*)d_in[31];
    const float* cs_Wo = (const float*)d_in[32]; const float* cs_bo = (const float*)d_in[33];
    const float* mlp_W = (const float*)d_in[34];
    const float* mlp_b = (const float*)d_in[35];

    unsigned short* wsu = (unsigned short*)d_ws;
    unsigned short* st_fb  = wsu;
    unsigned short* exp_fb = st_fb + (size_t)B_SZ * L_SEQ * DMODEL;
    unsigned short* xbuf   = exp_fb + (size_t)B_SZ * L_SEQ * DMODEL;
    unsigned short* wtbuf  = xbuf + (size_t)2048 * 2048;
    unsigned short* winT_st = wtbuf + (size_t)1024 * 2048;
    unsigned short* winT_ex = winT_st + (size_t)NPAD * 128;
    unsigned short* woutT_st = winT_ex + (size_t)NPAD * 128;
    unsigned short* woutT_ex = woutT_st + (size_t)128 * 256;
    unsigned short* attnWT  = woutT_ex + (size_t)128 * 256;

    prep_weights<<<1424, 256, 0, stream>>>(
        st_Win, ex_Win, st_Wout, ex_Wout, st_normw, ex_normw,
        cs_Wq, cs_Wk, cs_Wv, cs_Wo, cx_Wq, cx_Wk, cx_Wv, cx_Wo,
        winT_st, winT_ex, woutT_st, woutT_ex, attnWT);
    mamba_dual<<<3072, 256, 0, stream>>>(
        exp_feature, st_feature, winT_ex, winT_st,
        ex_convw, st_convw, ex_convb, st_convb,
        ex_dtb, st_dtb, ex_Alog, st_Alog, ex_D, st_D,
        woutT_ex, woutT_st,
        exp_fb, st_fb,
        mlp_W, wtbuf);
    attn_kernel<<<B_SZ / 4, 256, 0, stream>>>(st_fb, exp_fb, attnWT,
                                              cs_bq, cs_bk, cs_bv, cs_bo,
                                              cx_bq, cx_bk, cx_bv, cx_bo,
                                              (__hip_bfloat16*)xbuf);
    {
        dim3 g(1024 / 64, 2048 / 64);
        mlp_mfma<<<g, 256, 0, stream>>>(xbuf, wtbuf, mlp_b, (float*)d_out);
    }
}

// Round 12
// 238.060 us; speedup vs baseline: 1.0282x; 1.0282x over previous
//
#include <hip/hip_runtime.h>
#include <hip/hip_bf16.h>
#include <math.h>

#define B_SZ 2048
#define L_SEQ 8
#define DMODEL 128
#define DSTATE 64
#define HEADDIM 32
#define DCONV 4
#define DINNER 256
#define NHEADS 8
#define DCONVCH 384   // DINNER + 2*DSTATE
#define DINPROJ 648   // 2*DINNER + 2*DSTATE + NHEADS
#define NPAD 656      // 41 * 16

typedef short bf16x8 __attribute__((ext_vector_type(8)));
typedef float floatx4 __attribute__((ext_vector_type(4)));

__device__ __forceinline__ float siluf(float x) {
    return x / (1.f + expf(-x));
}
__device__ __forceinline__ float bf2f(unsigned short h) {
    unsigned int u = ((unsigned int)h) << 16;
    return __builtin_bit_cast(float, u);
}
__device__ __forceinline__ unsigned short f2bf(float f) {
    __hip_bfloat16 b = __float2bfloat16(f);
    return __builtin_bit_cast(unsigned short, b);
}
__device__ __forceinline__ void unpack8(bf16x8 v, float* o) {
    #pragma unroll
    for (int j = 0; j < 8; ++j) o[j] = bf2f((unsigned short)v[j]);
}
// async global->LDS, 16B per lane; LDS dest = wave-uniform base + lane*16
__device__ __forceinline__ void gl_lds16(const unsigned short* g, unsigned short* l) {
    __builtin_amdgcn_global_load_lds(
        (const __attribute__((address_space(1))) unsigned int*)g,
        (__attribute__((address_space(3))) unsigned int*)l, 16, 0, 0);
}

// ---------------------------------------------------------------------------
// Prep (small): Win/Wout/attn transposes+casts. 1424 blocks. (frozen)
// ---------------------------------------------------------------------------
__global__ __launch_bounds__(256) void prep_weights(
    const float* __restrict__ st_Win, const float* __restrict__ ex_Win,
    const float* __restrict__ st_Wout, const float* __restrict__ ex_Wout,
    const float* __restrict__ st_normw, const float* __restrict__ ex_normw,
    const float* __restrict__ cs_Wq, const float* __restrict__ cs_Wk,
    const float* __restrict__ cs_Wv, const float* __restrict__ cs_Wo,
    const float* __restrict__ cx_Wq, const float* __restrict__ cx_Wk,
    const float* __restrict__ cx_Wv, const float* __restrict__ cx_Wo,
    unsigned short* __restrict__ winT_st, unsigned short* __restrict__ winT_ex,
    unsigned short* __restrict__ woutT_st, unsigned short* __restrict__ woutT_ex,
    unsigned short* __restrict__ attnWT)
{
    int blk = blockIdx.x;
    if (blk < 656) {
        const float* src = blk < 328 ? st_Win : ex_Win;
        unsigned short* dst = blk < 328 ? winT_st : winT_ex;
        int idx = (blk % 328) * 256 + threadIdx.x;
        if (idx >= NPAD * 128) return;
        int n = idx / 128, k = idx % 128;
        float v = (n < DINPROJ) ? src[k * DINPROJ + n] : 0.f;
        dst[idx] = f2bf(v);
    } else if (blk < 912) {
        const float* src = blk < 784 ? st_Wout : ex_Wout;
        const float* nw  = blk < 784 ? st_normw : ex_normw;
        unsigned short* dst = blk < 784 ? woutT_st : woutT_ex;
        int idx = ((blk - 656) % 128) * 256 + threadIdx.x;
        int n = idx / 256, k = idx % 256;   // dst [128][256]
        dst[idx] = f2bf(src[k * 128 + n] * nw[k]);   // normw folded into Wout
    } else {
        int b2 = blk - 912;
        int mat = b2 >> 6;
        const float* src = mat == 0 ? cs_Wq : mat == 1 ? cs_Wk : mat == 2 ? cs_Wv :
                           mat == 3 ? cs_Wo : mat == 4 ? cx_Wq : mat == 5 ? cx_Wk :
                           mat == 6 ? cx_Wv : cx_Wo;
        int e = (b2 & 63) * 256 + threadIdx.x;
        int n = e >> 7, k = e & 127;
        attnWT[mat * 16384 + n * 128 + k] = f2bf(src[k * 128 + n]);
    }
}

// ---------------------------------------------------------------------------
// Dual Mamba2 v4 (frozen from R8/R10): GEMM1 deduplicated. Register prefetch
// (R9) was a NULL — do not retry. + backfilled mlp_W transpose.
// ---------------------------------------------------------------------------
#define LDK 136
#define LDZ 648
__global__ __launch_bounds__(256, 3) void mamba_dual(
    const float* __restrict__ u_ex, const float* __restrict__ u_st,
    const unsigned short* __restrict__ WinT_ex, const unsigned short* __restrict__ WinT_st,
    const float* __restrict__ convw_ex, const float* __restrict__ convw_st,
    const float* __restrict__ convb_ex, const float* __restrict__ convb_st,
    const float* __restrict__ dtb_ex, const float* __restrict__ dtb_st,
    const float* __restrict__ Alog_ex, const float* __restrict__ Alog_st,
    const float* __restrict__ Dp_ex, const float* __restrict__ Dp_st,
    const unsigned short* __restrict__ WoutT_ex, const unsigned short* __restrict__ WoutT_st,
    unsigned short* __restrict__ out_ex, unsigned short* __restrict__ out_st,
    const float* __restrict__ mlp_W, unsigned short* __restrict__ mlpWt)
{
    const int tid = threadIdx.x;

    __shared__ __align__(16) unsigned short uA[32 * LDK];  // A-frags; coefp+rstd; transpose tile
    __shared__ __align__(16) unsigned short zx[32 * LDZ];
    __shared__ float dtv[4][8][8];
    __shared__ float cum[4][8][8];
    __shared__ float Gm[4][8][8];

    if (blockIdx.x >= 1024) {
        // ---- mlp_W transpose backfill: 2048 blocks of 32x32 ----
        int b2 = blockIdx.x - 1024;
        int n0 = (b2 & 31) * 32, k0 = (b2 >> 5) * 32;
        float* tile = (float*)uA;            // 32*33 floats = 4224 B
        const int c = tid & 31, r0 = tid >> 5;
        for (int rr = r0; rr < 32; rr += 8)
            tile[rr * 33 + c] = mlp_W[(size_t)(k0 + rr) * 1024 + n0 + c];
        __syncthreads();
        for (int rr = r0; rr < 32; rr += 8)
            mlpWt[(size_t)(n0 + rr) * 2048 + k0 + c] = f2bf(tile[c * 33 + rr]);
        return;
    }

    const int which = blockIdx.x >> 9;          // 1024 blocks: 512 per input
    const float* u = which ? u_st : u_ex;
    const unsigned short* WinT = which ? WinT_st : WinT_ex;
    const float* convw = which ? convw_st : convw_ex;
    const float* convb = which ? convb_st : convb_ex;
    const float* dtb = which ? dtb_st : dtb_ex;
    const float* Alog = which ? Alog_st : Alog_ex;
    const float* Dp = which ? Dp_st : Dp_ex;
    const unsigned short* WoutT = which ? WoutT_st : WoutT_ex;
    unsigned short* outf = which ? out_st : out_ex;

    const int lane = tid & 63;
    const int wave = tid >> 6;
    const int l15 = lane & 15;
    const int q8 = (lane >> 4) * 8;
    const int row0 = (lane >> 4) * 4;
    const int grow0 = (blockIdx.x & 511) * 32;  // 32 rows per block

    float* coefp = (float*)uA;          // 2048 floats (8192 B of 8704)
    float* rstdp = coefp + 2048;        // 32 floats

    // stage u (32 rows x 128) as bf16 A-tiles
    #pragma unroll
    for (int it = 0; it < 4; ++it) {
        int i = tid + it * 256;
        int r = i >> 5, k4 = (i & 31) * 4;
        float4 v = *(const float4*)(u + (size_t)(grow0 + r) * DMODEL + k4);
        ushort4 h;
        h.x = f2bf(v.x); h.y = f2bf(v.y); h.z = f2bf(v.z); h.w = f2bf(v.w);
        *(ushort4*)(uA + r * LDK + k4) = h;
    }
    __syncthreads();

    // GEMM1: zxbcdt = u @ Win. Loop over nt only; one B load, two m-tile MFMAs.
    {
        bf16x8 af[2][4];
        #pragma unroll
        for (int mt = 0; mt < 2; ++mt)
            #pragma unroll
            for (int kk = 0; kk < 4; ++kk)
                af[mt][kk] = *(const bf16x8*)(uA + (mt * 16 + l15) * LDK + kk * 32 + q8);
        for (int nt = wave; nt < 41; nt += 4) {
            const unsigned short* bp = WinT + (size_t)(nt * 16 + l15) * 128 + q8;
            bf16x8 bfr[4];
            #pragma unroll
            for (int kk = 0; kk < 4; ++kk) bfr[kk] = *(const bf16x8*)(bp + kk * 32);
            floatx4 acc0 = {0.f, 0.f, 0.f, 0.f};
            floatx4 acc1 = {0.f, 0.f, 0.f, 0.f};
            #pragma unroll
            for (int kk = 0; kk < 4; ++kk) {
                acc0 = __builtin_amdgcn_mfma_f32_16x16x32_bf16(af[0][kk], bfr[kk], acc0, 0, 0, 0);
                acc1 = __builtin_amdgcn_mfma_f32_16x16x32_bf16(af[1][kk], bfr[kk], acc1, 0, 0, 0);
            }
            if (nt == 40) {
                if (l15 < 8) {
                    float dbv = dtb[l15];
                    #pragma unroll
                    for (int r = 0; r < 4; ++r) {
                        int rr0 = row0 + r;
                        float v0 = acc0[r] + dbv;
                        dtv[rr0 >> 3][rr0 & 7][l15] = (v0 > 20.f) ? v0 : log1pf(expf(v0));
                        int rr1 = 16 + row0 + r;
                        float v1 = acc1[r] + dbv;
                        dtv[rr1 >> 3][rr1 & 7][l15] = (v1 > 20.f) ? v1 : log1pf(expf(v1));
                    }
                }
            } else {
                #pragma unroll
                for (int r = 0; r < 4; ++r) {
                    zx[(row0 + r) * LDZ + nt * 16 + l15]      = f2bf(acc0[r]);
                    zx[(16 + row0 + r) * LDZ + nt * 16 + l15] = f2bf(acc1[r]);
                }
            }
        }
    }
    __syncthreads();

    // depthwise conv + SiLU over 32 rows x 384 channels (= 1536 ch-groups)
    float cv[6][8];
    {
        #pragma unroll
        for (int it = 0; it < 6; ++it) {
            int i = tid + it * 256;
            int r = i / 48, g = i % 48;
            int c0 = g * 8;
            int l = r & 7, bloc = r >> 3;
            float s[8];
            float4 cb0 = *(const float4*)(convb + c0);
            float4 cb1 = *(const float4*)(convb + c0 + 4);
            s[0] = cb0.x; s[1] = cb0.y; s[2] = cb0.z; s[3] = cb0.w;
            s[4] = cb1.x; s[5] = cb1.y; s[6] = cb1.z; s[7] = cb1.w;
            #pragma unroll
            for (int k = 0; k < DCONV; ++k) {
                int lp = l + k - (DCONV - 1);
                if (lp >= 0) {
                    bf16x8 v = *(const bf16x8*)(zx + (bloc * 8 + lp) * LDZ + 256 + c0);
                    float vf[8];
                    unpack8(v, vf);
                    float4 w0 = *(const float4*)(convw + k * DCONVCH + c0);
                    float4 w1 = *(const float4*)(convw + k * DCONVCH + c0 + 4);
                    s[0] += vf[0] * w0.x; s[1] += vf[1] * w0.y;
                    s[2] += vf[2] * w0.z; s[3] += vf[3] * w0.w;
                    s[4] += vf[4] * w1.x; s[5] += vf[5] * w1.y;
                    s[6] += vf[6] * w1.z; s[7] += vf[7] * w1.w;
                }
            }
            #pragma unroll
            for (int j = 0; j < 8; ++j) cv[it][j] = siluf(s[j]);
        }
    }
    __syncthreads();
    {
        #pragma unroll
        for (int it = 0; it < 6; ++it) {
            int i = tid + it * 256;
            int r = i / 48, c0 = (i % 48) * 8;
            bf16x8 o;
            #pragma unroll
            for (int j = 0; j < 8; ++j) o[j] = (short)f2bf(cv[it][j]);
            *(bf16x8*)(zx + r * LDZ + 256 + c0) = o;
        }
        if (tid < 32) {  // dt cumsum (dtv ready since GEMM1 barrier)
            int bloc = tid >> 3, h = tid & 7;
            float c = 0.f;
            for (int l = 0; l < L_SEQ; ++l) { c += dtv[bloc][l][h]; cum[bloc][l][h] = c; }
        }
    }
    __syncthreads();

    // Gram matrix G[t][s] = B_s . C_t  (4 blocs x 8 x 8 = 256 threads)
    {
        int bloc = tid >> 6, t = (tid >> 3) & 7, s = tid & 7;
        float a = 0.f;
        #pragma unroll
        for (int n = 0; n < DSTATE; n += 8) {
            bf16x8 bv = *(const bf16x8*)(zx + (bloc * 8 + s) * LDZ + 512 + n);
            bf16x8 cvv = *(const bf16x8*)(zx + (bloc * 8 + t) * LDZ + 576 + n);
            float bf_[8], cf_[8];
            unpack8(bv, bf_); unpack8(cvv, cf_);
            #pragma unroll
            for (int j = 0; j < 8; ++j) a += bf_[j] * cf_[j];
        }
        Gm[bloc][t][s] = a;
    }
    __syncthreads();

    // coef[t][s][h] = G[t][s] * exp(A*(cum_t - cum_s)) * dt_s   (2048 entries)
    #pragma unroll
    for (int it = 0; it < 8; ++it) {
        int i = tid + it * 256;
        int bloc = i >> 9, t = (i >> 6) & 7, s = (i >> 3) & 7, h = i & 7;
        float A = -expf(Alog[h]);
        coefp[i] = (s <= t)
            ? Gm[bloc][t][s] * expf(A * (cum[bloc][t][h] - cum[bloc][s][h])) * dtv[bloc][s][h]
            : 0.f;
    }
    __syncthreads();

    // SSM y-accum + gate + sum-of-squares, all in registers (4 sub-iters)
    float pj[4];
    bf16x8 yo[4];
    int rF[4], c0F[4];
    {
        #pragma unroll
        for (int it = 0; it < 4; ++it) {
            int i = tid + it * 256;
            int r = i >> 5, g = i & 31;
            int c0 = g * 8, h = g >> 2;
            int bloc = r >> 3, t = r & 7;
            float acc[8];
            {
                bf16x8 xv = *(const bf16x8*)(zx + r * LDZ + 256 + c0);
                float xf[8]; unpack8(xv, xf);
                float d = Dp[h];
                #pragma unroll
                for (int j = 0; j < 8; ++j) acc[j] = d * xf[j];
            }
            for (int s = 0; s <= t; ++s) {
                float cf = coefp[((bloc * 8 + t) * 8 + s) * 8 + h];
                bf16x8 xv = *(const bf16x8*)(zx + (bloc * 8 + s) * LDZ + 256 + c0);
                float xf[8]; unpack8(xv, xf);
                #pragma unroll
                for (int j = 0; j < 8; ++j) acc[j] += cf * xf[j];
            }
            bf16x8 zv = *(const bf16x8*)(zx + r * LDZ + c0);
            float zf[8]; unpack8(zv, zf);
            float p = 0.f;
            #pragma unroll
            for (int j = 0; j < 8; ++j) {
                float y = acc[j] * siluf(zf[j]);
                p += y * y;
                yo[it][j] = (short)f2bf(y);
            }
            pj[it] = p; rF[it] = r; c0F[it] = c0;
        }
    }
    // row sum-of-squares: each 32-lane half shares one row -> butterfly reduce
    #pragma unroll
    for (int m = 1; m < 32; m <<= 1) {
        #pragma unroll
        for (int it = 0; it < 4; ++it) pj[it] += __shfl_xor(pj[it], m);
    }
    if ((tid & 31) == 0) {
        #pragma unroll
        for (int it = 0; it < 4; ++it)
            rstdp[rF[it]] = rsqrtf(pj[it] * (1.f / 256.f) + 1e-5f);
    }
    __syncthreads();   // all x-reads done + rstd visible
    #pragma unroll
    for (int it = 0; it < 4; ++it)
        *(bf16x8*)(zx + rF[it] * LDZ + 256 + c0F[it]) = yo[it];
    __syncthreads();

    // GEMM2: out = rstd[row] * (y @ WoutT') (2 m-tiles x 8 n-tiles)
    {
        bf16x8 af[2][8];
        #pragma unroll
        for (int mt = 0; mt < 2; ++mt)
            #pragma unroll
            for (int kk = 0; kk < 8; ++kk)
                af[mt][kk] = *(const bf16x8*)(zx + (mt * 16 + l15) * LDZ + 256 + kk * 32 + q8);
        #pragma unroll
        for (int ni = 0; ni < 2; ++ni) {
            int nt = wave * 2 + ni;
            const unsigned short* bp = WoutT + (size_t)(nt * 16 + l15) * 256 + q8;
            bf16x8 bfr[8];
            #pragma unroll
            for (int kk = 0; kk < 8; ++kk) bfr[kk] = *(const bf16x8*)(bp + kk * 32);
            #pragma unroll
            for (int mt = 0; mt < 2; ++mt) {
                floatx4 acc = {0.f, 0.f, 0.f, 0.f};
                #pragma unroll
                for (int kk = 0; kk < 8; ++kk)
                    acc = __builtin_amdgcn_mfma_f32_16x16x32_bf16(af[mt][kk], bfr[kk], acc, 0, 0, 0);
                #pragma unroll
                for (int r = 0; r < 4; ++r) {
                    int rr = mt * 16 + row0 + r;
                    outf[(size_t)(grow0 + rr) * DMODEL + nt * 16 + l15] =
                        f2bf(acc[r] * rstdp[rr]);
                }
            }
        }
    }
}

// ---------------------------------------------------------------------------
// Cross-attentions, 4 batches per block (M=32), grid B/4 = 512.
// v3 (frozen from R10): attv aliased onto Qs (3 blocks/CU) + wave-parallel
// softmax; P zero-band pre-initialized once.
// ---------------------------------------------------------------------------
#define ASTR 136
#define VSTR 40
#define PSTR 40
__global__ __launch_bounds__(256, 3) void attn_kernel(
    const unsigned short* __restrict__ st_f,
    const unsigned short* __restrict__ exp_f,
    const unsigned short* __restrict__ WT,
    const float* __restrict__ cs_bq, const float* __restrict__ cs_bk,
    const float* __restrict__ cs_bv, const float* __restrict__ cs_bo,
    const float* __restrict__ cx_bq, const float* __restrict__ cx_bk,
    const float* __restrict__ cx_bv, const float* __restrict__ cx_bo,
    __hip_bfloat16* __restrict__ x)
{
    const int tid = threadIdx.x;
    const int lane = tid & 63, wave = tid >> 6;
    const int l15 = lane & 15;
    const int q8 = (lane >> 4) * 8;
    const int row0 = (lane >> 4) * 4;
    const int grow0 = blockIdx.x * 32;
    const int b0 = blockIdx.x * 4;
    const float scale = 0.08838834764831845f;

    __shared__ __align__(16) unsigned short stf[32 * ASTR];
    __shared__ __align__(16) unsigned short exf[32 * ASTR];
    __shared__ __align__(16) unsigned short Qs[32 * ASTR];   // aliased by attv
    __shared__ __align__(16) unsigned short Ks[32 * ASTR];
    __shared__ __align__(16) unsigned short Vt[128 * VSTR];  // [chan][kvrow 0..31]
    __shared__ __align__(16) unsigned short P[32 * PSTR];
    __shared__ float Ss[32][33];
    unsigned short* attv = Qs;   // Qs last read in scores; attv written post-barrier

    #pragma unroll
    for (int it = 0; it < 2; ++it) {
        int i = tid + it * 256;
        int r = i >> 4, c8 = (i & 15) * 8;
        *(uint4*)(stf + r * ASTR + c8) = *(const uint4*)(st_f + (size_t)(grow0 + r) * 128 + c8);
        *(uint4*)(exf + r * ASTR + c8) = *(const uint4*)(exp_f + (size_t)(grow0 + r) * 128 + c8);
    }
    // P zero-band init (once): the per-row nonzero band is pass-invariant.
    #pragma unroll
    for (int i = tid; i < 32 * 32; i += 256)
        P[(i >> 5) * PSTR + (i & 31)] = 0;
    __syncthreads();

    #pragma unroll
    for (int pass = 0; pass < 2; ++pass) {
        const unsigned short* qsrc = pass ? exf : stf;
        const unsigned short* kvsrc = pass ? stf : exf;
        const unsigned short* Wq = WT + (size_t)pass * 4 * 16384;
        const unsigned short* Wk = Wq + 16384;
        const unsigned short* Wv = Wq + 32768;
        const unsigned short* Wo = Wq + 49152;
        const float* bq = pass ? cx_bq : cs_bq;
        const float* bk = pass ? cx_bk : cs_bk;
        const float* bv = pass ? cx_bv : cs_bv;
        const float* bo = pass ? cx_bo : cs_bo;

        // --- Q/K/V projections (2 m-tiles x 2 n-tiles per wave) ---
        {
            bf16x8 aq[2][4], akv[2][4];
            #pragma unroll
            for (int mt = 0; mt < 2; ++mt)
                #pragma unroll
                for (int kk = 0; kk < 4; ++kk) {
                    aq[mt][kk]  = *(const bf16x8*)(qsrc  + (mt * 16 + l15) * ASTR + kk * 32 + q8);
                    akv[mt][kk] = *(const bf16x8*)(kvsrc + (mt * 16 + l15) * ASTR + kk * 32 + q8);
                }
            #pragma unroll
            for (int ni = 0; ni < 2; ++ni) {
                int nc = (wave * 2 + ni) * 16 + l15;
                floatx4 aq0 = {0,0,0,0}, aq1 = {0,0,0,0};
                floatx4 ak0 = {0,0,0,0}, ak1 = {0,0,0,0};
                floatx4 av0 = {0,0,0,0}, av1 = {0,0,0,0};
                #pragma unroll
                for (int kk = 0; kk < 4; ++kk) {
                    bf16x8 wqf = *(const bf16x8*)(Wq + (size_t)nc * 128 + kk * 32 + q8);
                    bf16x8 wkf = *(const bf16x8*)(Wk + (size_t)nc * 128 + kk * 32 + q8);
                    bf16x8 wvf = *(const bf16x8*)(Wv + (size_t)nc * 128 + kk * 32 + q8);
                    aq0 = __builtin_amdgcn_mfma_f32_16x16x32_bf16(aq[0][kk],  wqf, aq0, 0, 0, 0);
                    aq1 = __builtin_amdgcn_mfma_f32_16x16x32_bf16(aq[1][kk],  wqf, aq1, 0, 0, 0);
                    ak0 = __builtin_amdgcn_mfma_f32_16x16x32_bf16(akv[0][kk], wkf, ak0, 0, 0, 0);
                    ak1 = __builtin_amdgcn_mfma_f32_16x16x32_bf16(akv[1][kk], wkf, ak1, 0, 0, 0);
                    av0 = __builtin_amdgcn_mfma_f32_16x16x32_bf16(akv[0][kk], wvf, av0, 0, 0, 0);
                    av1 = __builtin_amdgcn_mfma_f32_16x16x32_bf16(akv[1][kk], wvf, av1, 0, 0, 0);
                }
                float bqv = bq[nc], bkv = bk[nc], bvv = bv[nc];
                #pragma unroll
                for (int r = 0; r < 4; ++r) {
                    Qs[(row0 + r) * ASTR + nc]      = f2bf(aq0[r] + bqv);
                    Qs[(16 + row0 + r) * ASTR + nc] = f2bf(aq1[r] + bqv);
                    Ks[(row0 + r) * ASTR + nc]      = f2bf(ak0[r] + bkv);
                    Ks[(16 + row0 + r) * ASTR + nc] = f2bf(ak1[r] + bkv);
                    Vt[nc * VSTR + row0 + r]        = f2bf(av0[r] + bvv);
                    Vt[nc * VSTR + 16 + row0 + r]   = f2bf(av1[r] + bvv);
                }
            }
        }
        __syncthreads();

        // --- scores: S(32x32) = Q @ K^T; wave w does tile (w>>1, w&1) ---
        {
            int mtS = wave >> 1, ntS = wave & 1;
            floatx4 s = {0,0,0,0};
            #pragma unroll
            for (int kk = 0; kk < 4; ++kk) {
                bf16x8 a = *(const bf16x8*)(Qs + (mtS * 16 + l15) * ASTR + kk * 32 + q8);
                bf16x8 b = *(const bf16x8*)(Ks + (ntS * 16 + l15) * ASTR + kk * 32 + q8);
                s = __builtin_amdgcn_mfma_f32_16x16x32_bf16(a, b, s, 0, 0, 0);
            }
            #pragma unroll
            for (int r = 0; r < 4; ++r)
                Ss[mtS * 16 + row0 + r][ntS * 16 + l15] = s[r];
        }
        __syncthreads();

        // --- softmax, wave-parallel: thread = (row r, col c); 8-lane groups ---
        {
            int r = tid >> 3, c = tid & 7, c0 = (r >> 3) * 8;
            float v = Ss[r][c0 + c] * scale;
            float mx = v;
            mx = fmaxf(mx, __shfl_xor(mx, 1));
            mx = fmaxf(mx, __shfl_xor(mx, 2));
            mx = fmaxf(mx, __shfl_xor(mx, 4));
            float e = expf(v - mx);
            float sum = e;
            sum += __shfl_xor(sum, 1);
            sum += __shfl_xor(sum, 2);
            sum += __shfl_xor(sum, 4);
            P[r * PSTR + c0 + c] = f2bf(e / sum);
        }
        __syncthreads();

        // --- O = P(32x32) @ V(32x128): per wave 2 n-tiles x 2 m-tiles ---
        {
            #pragma unroll
            for (int ni = 0; ni < 2; ++ni) {
                int nc = (wave * 2 + ni) * 16 + l15;
                bf16x8 bv_ = *(const bf16x8*)(Vt + nc * VSTR + q8);
                #pragma unroll
                for (int mt = 0; mt < 2; ++mt) {
                    bf16x8 ap = *(const bf16x8*)(P + (mt * 16 + l15) * PSTR + q8);
                    floatx4 o = {0,0,0,0};
                    o = __builtin_amdgcn_mfma_f32_16x16x32_bf16(ap, bv_, o, 0, 0, 0);
                    #pragma unroll
                    for (int r = 0; r < 4; ++r)
                        attv[(mt * 16 + row0 + r) * ASTR + nc] = f2bf(o[r]);
                }
            }
        }
        __syncthreads();

        // --- Wo projection -> x ---
        {
            bf16x8 ao[2][4];
            #pragma unroll
            for (int mt = 0; mt < 2; ++mt)
                #pragma unroll
                for (int kk = 0; kk < 4; ++kk)
                    ao[mt][kk] = *(const bf16x8*)(attv + (mt * 16 + l15) * ASTR + kk * 32 + q8);
            #pragma unroll
            for (int ni = 0; ni < 2; ++ni) {
                int nc = (wave * 2 + ni) * 16 + l15;
                floatx4 a0 = {0,0,0,0}, a1 = {0,0,0,0};
                #pragma unroll
                for (int kk = 0; kk < 4; ++kk) {
                    bf16x8 wof = *(const bf16x8*)(Wo + (size_t)nc * 128 + kk * 32 + q8);
                    a0 = __builtin_amdgcn_mfma_f32_16x16x32_bf16(ao[0][kk], wof, a0, 0, 0, 0);
                    a1 = __builtin_amdgcn_mfma_f32_16x16x32_bf16(ao[1][kk], wof, a1, 0, 0, 0);
                }
                float bov = bo[nc];
                #pragma unroll
                for (int r = 0; r < 4; ++r) {
                    int rr0 = row0 + r;
                    int rr1 = 16 + row0 + r;
                    x[(size_t)(b0 + (rr0 >> 3)) * 2048 + (rr0 & 7) * 256 + pass * 128 + nc] =
                        __float2bfloat16(a0[r] + bov);
                    x[(size_t)(b0 + (rr1 >> 3)) * 2048 + (rr1 & 7) * 256 + pass * 128 + nc] =
                        __float2bfloat16(a1[r] + bov);
                }
            }
        }
        __syncthreads();
    }
}

// ---------------------------------------------------------------------------
// MLP via MFMA v5 (restored — best config): 64x64 tile, BK=64, 2-deep
// counted-vmcnt pipeline (T3+T4). 512 blocks. NOTE R11: 4-deep/vmcnt(12)
// with 64 KB LDS regressed ~3 us — loads are L2-covered; 2-deep is optimal.
// ---------------------------------------------------------------------------
__global__ __launch_bounds__(256, 4) void mlp_mfma(
    const unsigned short* __restrict__ X,   // [2048][2048] bf16
    const unsigned short* __restrict__ Wt,  // [1024][2048] bf16
    const float* __restrict__ bias,
    float* __restrict__ out)                // [2048][1024]
{
    __shared__ __align__(16) unsigned short As[2][64 * 64];
    __shared__ __align__(16) unsigned short Bs[2][64 * 64];
    const int tid = threadIdx.x;
    const int wave = tid >> 6, lane = tid & 63;
    const int wm = (wave >> 1) * 32, wn = (wave & 1) * 32;
    const int bm = blockIdx.y * 64, bn = blockIdx.x * 64;
    const int l15 = lane & 15, q8 = (lane >> 4) * 8;

    const int c0i = tid, c1i = tid + 256;
    const int r0s = c0i >> 3, c0s = ((c0i & 7) ^ (r0s & 7)) * 8;
    const int r1s = c1i >> 3, c1s = ((c1i & 7) ^ (r1s & 7)) * 8;
    const unsigned short* gA0 = X + (size_t)(bm + r0s) * 2048 + c0s;
    const unsigned short* gA1 = X + (size_t)(bm + r1s) * 2048 + c1s;
    const unsigned short* gB0 = Wt + (size_t)(bn + r0s) * 2048 + c0s;
    const unsigned short* gB1 = Wt + (size_t)(bn + r1s) * 2048 + c1s;

    floatx4 acc[2][2];
    #pragma unroll
    for (int i = 0; i < 2; ++i)
        #pragma unroll
        for (int j = 0; j < 2; ++j) acc[i][j] = (floatx4){0.f, 0.f, 0.f, 0.f};

    const int ra0 = wm + l15, ra1 = wm + 16 + l15;
    const int rb0 = wn + l15, rb1 = wn + 16 + l15;

    // prologue: tiles 0 and 1 in flight (tile-grouped: oldest 4 = tile 0)
    gl_lds16(gA0, As[0] + c0i * 8);
    gl_lds16(gA1, As[0] + c1i * 8);
    gl_lds16(gB0, Bs[0] + c0i * 8);
    gl_lds16(gB1, Bs[0] + c1i * 8);
    gl_lds16(gA0 + 64, As[1] + c0i * 8);
    gl_lds16(gA1 + 64, As[1] + c1i * 8);
    gl_lds16(gB0 + 64, Bs[1] + c0i * 8);
    gl_lds16(gB1 + 64, Bs[1] + c1i * 8);

#define MLP_COMPUTE(Ac, Bc)                                                    \
    {                                                                          \
        _Pragma("unroll")                                                      \
        for (int ks = 0; ks < 2; ++ks) {                                       \
            int xx = ks * 4 + (q8 >> 3);                                       \
            bf16x8 a0 = *(const bf16x8*)((Ac) + (ra0 * 8 + (xx ^ (ra0 & 7))) * 8); \
            bf16x8 a1 = *(const bf16x8*)((Ac) + (ra1 * 8 + (xx ^ (ra1 & 7))) * 8); \
            bf16x8 b0 = *(const bf16x8*)((Bc) + (rb0 * 8 + (xx ^ (rb0 & 7))) * 8); \
            bf16x8 b1 = *(const bf16x8*)((Bc) + (rb1 * 8 + (xx ^ (rb1 & 7))) * 8); \
            acc[0][0] = __builtin_amdgcn_mfma_f32_16x16x32_bf16(a0, b0, acc[0][0], 0, 0, 0); \
            acc[0][1] = __builtin_amdgcn_mfma_f32_16x16x32_bf16(a0, b1, acc[0][1], 0, 0, 0); \
            acc[1][0] = __builtin_amdgcn_mfma_f32_16x16x32_bf16(a1, b0, acc[1][0], 0, 0, 0); \
            acc[1][1] = __builtin_amdgcn_mfma_f32_16x16x32_bf16(a1, b1, acc[1][1], 0, 0, 0); \
        }                                                                      \
    }

    // main loop: t = 0..29; compute tile t from buf t&1, refill with t+2
    for (int t = 0; t < 30; ++t) {
        asm volatile("s_waitcnt vmcnt(4)" ::: "memory");   // my tile-t loads landed
        __builtin_amdgcn_sched_barrier(0);
        __builtin_amdgcn_s_barrier();                      // everyone's landed; buf free
        const unsigned short* Ac = As[t & 1];
        const unsigned short* Bc = Bs[t & 1];
        MLP_COMPUTE(Ac, Bc)
        __builtin_amdgcn_sched_barrier(0);
        __builtin_amdgcn_s_barrier();                      // all reads of buf t&1 done
        int k0 = (t + 2) * 64;
        unsigned short* An = As[t & 1];
        unsigned short* Bn = Bs[t & 1];
        gl_lds16(gA0 + k0, An + c0i * 8);
        gl_lds16(gA1 + k0, An + c1i * 8);
        gl_lds16(gB0 + k0, Bn + c0i * 8);
        gl_lds16(gB1 + k0, Bn + c1i * 8);
    }
    // t = 30: tiles 30,31 outstanding -> wait tile 30
    asm volatile("s_waitcnt vmcnt(4)" ::: "memory");
    __builtin_amdgcn_sched_barrier(0);
    __builtin_amdgcn_s_barrier();
    MLP_COMPUTE(As[0], Bs[0])
    // t = 31: drain tile 31
    asm volatile("s_waitcnt vmcnt(0)" ::: "memory");
    __builtin_amdgcn_sched_barrier(0);
    __builtin_amdgcn_s_barrier();
    MLP_COMPUTE(As[1], Bs[1])
#undef MLP_COMPUTE

    const int row0 = (lane >> 4) * 4;
    #pragma unroll
    for (int j = 0; j < 2; ++j) {
        int col = bn + wn + j * 16 + l15;
        float bv = bias[col];
        #pragma unroll
        for (int r = 0; r < 4; ++r) {
            out[(size_t)(bm + wm + row0 + r) * 1024 + col] = acc[0][j][r] + bv;
            out[(size_t)(bm + wm + 16 + row0 + r) * 1024 + col] = acc[1][j][r] + bv;
        }
    }
}

extern "C" void kernel_launch(void* const* d_in, const int* in_sizes, int n_in,
                              void* d_out, int out_size, void* d_ws, size_t ws_size,
                              hipStream_t stream) {
    const float* st_feature = (const float*)d_in[0];
    const float* exp_feature = (const float*)d_in[1];
    const float* st_Win = (const float*)d_in[2];
    const float* st_convw = (const float*)d_in[3];
    const float* st_convb = (const float*)d_in[4];
    const float* st_dtb = (const float*)d_in[5];
    const float* st_Alog = (const float*)d_in[6];
    const float* st_D = (const float*)d_in[7];
    const float* st_normw = (const float*)d_in[8];
    const float* st_Wout = (const float*)d_in[9];
    const float* ex_Win = (const float*)d_in[10];
    const float* ex_convw = (const float*)d_in[11];
    const float* ex_convb = (const float*)d_in[12];
    const float* ex_dtb = (const float*)d_in[13];
    const float* ex_Alog = (const float*)d_in[14];
    const float* ex_D = (const float*)d_in[15];
    const float* ex_normw = (const float*)d_in[16];
    const float* ex_Wout = (const float*)d_in[17];
    const float* cx_Wq = (const float*)d_in[18]; const float* cx_bq = (const float*)d_in[19];
    const float* cx_Wk = (const float*)d_in[20]; const float* cx_bk = (const float*)d_in[21];
    const float* cx_Wv = (const float*)d_in[22]; const float* cx_bv = (const float*)d_in[23];
    const float* cx_Wo = (const float*)d_in[24]; const float* cx_bo = (const float*)d_in[25];
    const float* cs_Wq = (const float*)d_in[26]; const float* cs_bq = (const float*)d_in[27];
    const float* cs_Wk = (const float*)d_in[28]; const float* cs_bk = (const float*)d_in[29];
    const float* cs_Wv = (const float*)d_in[30]; const float* cs_bv = (const float*)d_in[31];
    const float* cs_Wo = (const float*)d_in[32]; const float* cs_bo = (const float*)d_in[33];
    const float* mlp_W = (const float*)d_in[34];
    const float* mlp_b = (const float*)d_in[35];

    unsigned short* wsu = (unsigned short*)d_ws;
    unsigned short* st_fb  = wsu;
    unsigned short* exp_fb = st_fb + (size_t)B_SZ * L_SEQ * DMODEL;
    unsigned short* xbuf   = exp_fb + (size_t)B_SZ * L_SEQ * DMODEL;
    unsigned short* wtbuf  = xbuf + (size_t)2048 * 2048;
    unsigned short* winT_st = wtbuf + (size_t)1024 * 2048;
    unsigned short* winT_ex = winT_st + (size_t)NPAD * 128;
    unsigned short* woutT_st = winT_ex + (size_t)NPAD * 128;
    unsigned short* woutT_ex = woutT_st + (size_t)128 * 256;
    unsigned short* attnWT  = woutT_ex + (size_t)128 * 256;

    prep_weights<<<1424, 256, 0, stream>>>(
        st_Win, ex_Win, st_Wout, ex_Wout, st_normw, ex_normw,
        cs_Wq, cs_Wk, cs_Wv, cs_Wo, cx_Wq, cx_Wk, cx_Wv, cx_Wo,
        winT_st, winT_ex, woutT_st, woutT_ex, attnWT);
    mamba_dual<<<3072, 256, 0, stream>>>(
        exp_feature, st_feature, winT_ex, winT_st,
        ex_convw, st_convw, ex_convb, st_convb,
        ex_dtb, st_dtb, ex_Alog, st_Alog, ex_D, st_D,
        woutT_ex, woutT_st,
        exp_fb, st_fb,
        mlp_W, wtbuf);
    attn_kernel<<<B_SZ / 4, 256, 0, stream>>>(st_fb, exp_fb, attnWT,
                                              cs_bq, cs_bk, cs_bv, cs_bo,
                                              cx_bq, cx_bk, cx_bv, cx_bo,
                                              (__hip_bfloat16*)xbuf);
    {
        dim3 g(1024 / 64, 2048 / 64);
        mlp_mfma<<<g, 256, 0, stream>>>(xbuf, wtbuf, mlp_b, (float*)d_out);
    }
}